// Round 3
// baseline (654.257 us; speedup 1.0000x reference)
//
#include <hip/hip_runtime.h>

#define BB 2
#define NN 2000
#define GG 100
#define HH 800
#define WW 800
#define TT 200
#define PP 66
#define NEGN 134
#define MHH 28
#define MWW 28

// workspace layout (byte offsets) — tiny pos-descriptor table K1 -> K2
#define WS_BOX 0        // float4[BB*PP]  proposal box per pos slot (dequantized f32)
#define WS_OKG 2112     // int[BB*PP]     (g<<1)|ok
#define WS_MODE 2644    // int            mask encoding mode

enum { M_F32 = 0, M_BF16 = 1, M_I32 = 2, M_U8 = 3 };

__device__ __forceinline__ float bf16_to_f(unsigned short v) {
  return __uint_as_float(((unsigned int)v) << 16);
}

__device__ __forceinline__ float load_box_c(const void* p, long long elem, int mode) {
  if (mode == M_BF16) return bf16_to_f(((const unsigned short*)p)[elem]);
  return ((const float*)p)[elem];
}

__device__ __forceinline__ float load_mask(const void* p, size_t idx, int mode) {
  switch (mode) {
    case M_F32:  return ((const float*)p)[idx];
    case M_BF16: return ((const unsigned short*)p)[idx] ? 1.0f : 0.0f;
    case M_I32:  return ((const int*)p)[idx] ? 1.0f : 0.0f;
    default:     return ((const unsigned char*)p)[idx] ? 1.0f : 0.0f;
  }
}

__device__ __forceinline__ unsigned int ord_f32(float f) {
  unsigned int u = __float_as_uint(f);
  return (u & 0x80000000u) ? ~u : (u | 0x80000000u);
}

// ---- fused: sniff + IoU + flags + stable top-k + rois/class/deltas epilogue ----
// grid: BB*2 blocks (b = blk>>1, which = blk&1: 0=positives, 1=negatives)
__global__ void __launch_bounds__(1024)
fused_kernel(const void* props, const int* cls, const void* gtb,
             const unsigned int* props_u, const unsigned int* masks_u,
             float* out, float4* wbox, int* wokg, int* wmode) {
#pragma clang fp contract(off)
  __shared__ float gt0[GG], gt1[GG], gt2[GG], gt3[GG];
  __shared__ int gcls[GG];
  __shared__ float iouv[NN];
  __shared__ int meta[NN];                 // (argmax<<2) | flags
  __shared__ unsigned long long keys[2048];
  __shared__ int cnt[4];
  int tid = threadIdx.x;
  int b = blockIdx.x >> 1, which = blockIdx.x & 1;

  if (tid < 4) cnt[tid] = 0;
  __syncthreads();
  // --- box dtype sniff: 1024 words (props >= 32000 B in any encoding) ---
  {
    unsigned int w = props_u[tid];
    float flo = bf16_to_f((unsigned short)(w & 0xFFFFu));
    float fhi = bf16_to_f((unsigned short)(w >> 16));
    unsigned long long m = __ballot(flo >= 0.0f && flo <= 4.0f && fhi >= 0.0f && fhi <= 4.0f);
    if ((tid & 63) == 0) atomicAdd(&cnt[0], __popcll(m));
  }
  // --- mask dtype sniff (block 0 only; masks >= 128 MB in any encoding) ---
  if (blockIdx.x == 0) {
    unsigned int w = masks_u[tid];
    unsigned int lo = w & 0xFFFFu, hi = w >> 16;
    unsigned long long m1 = __ballot(w == 0u || w == 0x3F800000u);
    unsigned long long m2 = __ballot((lo == 0u || lo == 0x3F80u) && (hi == 0u || hi == 0x3F80u));
    unsigned long long m3 = __ballot(w <= 1u);
    if ((tid & 63) == 0) {
      atomicAdd(&cnt[1], __popcll(m1));
      atomicAdd(&cnt[2], __popcll(m2));
      atomicAdd(&cnt[3], __popcll(m3));
    }
  }
  __syncthreads();
  int bmode = (cnt[0] >= 700) ? M_BF16 : M_F32;   // bf16 data: 1024/1024 pass; f32 data: ~25%
  if (blockIdx.x == 0 && tid == 0) {
    int mm;
    if (cnt[1] >= 1000) mm = M_F32;        // f32-encoded bools pass bf16 test too: f32 first
    else if (cnt[2] >= 1000) mm = M_BF16;
    else if (cnt[3] >= 1000) mm = M_I32;   // i32 passes u8 test too: i32 first
    else mm = M_U8;
    *wmode = mm;
  }
  // --- stage GT boxes + classes to LDS ---
  if (tid < GG) {
    long long ge = (long long)(b * GG + tid) * 4;
    gt0[tid] = load_box_c(gtb, ge + 0, bmode);
    gt1[tid] = load_box_c(gtb, ge + 1, bmode);
    gt2[tid] = load_box_c(gtb, ge + 2, bmode);
    gt3[tid] = load_box_c(gtb, ge + 3, bmode);
    gcls[tid] = cls[b * GG + tid];
  }
  __syncthreads();
  // --- IoU max / argmax / flags per proposal ---
  for (int i = tid; i < NN; i += 1024) {
    long long e = (long long)(b * NN + i) * 4;
    float p0 = load_box_c(props, e + 0, bmode);
    float p1 = load_box_c(props, e + 1, bmode);
    float p2 = load_box_c(props, e + 2, bmode);
    float p3 = load_box_c(props, e + 3, bmode);
    float a1 = (p2 - p0) * (p3 - p1);
    float best = -1e30f; int bestg = 0; float crowdmax = -1.0f;
    for (int g = 0; g < GG; ++g) {
      float g0 = gt0[g], g1 = gt1[g], g2 = gt2[g], g3 = gt3[g];
      float yy1 = fmaxf(p0, g0), xx1 = fmaxf(p1, g1);
      float yy2 = fminf(p2, g2), xx2 = fminf(p3, g3);
      float ih = yy2 - yy1; if (ih < 0.0f) ih = 0.0f;
      float iw = xx2 - xx1; if (iw < 0.0f) iw = 0.0f;
      float inter = ih * iw;
      float a2 = (g2 - g0) * (g3 - g1);
      float uni = (a1 + a2) - inter;
      float iou = inter / fmaxf(uni, 1e-12f);
      bool crowd = gcls[g] < 0;
      float ov = crowd ? -1.0f : iou;
      if (ov > best) { best = ov; bestg = g; }   // strict > == jnp.argmax first-max
      float cv = crowd ? iou : -1.0f;
      if (cv > crowdmax) crowdmax = cv;
    }
    int f = 0;
    if (best >= 0.5f) f |= 1;
    if (best < 0.5f && crowdmax < 0.001f) f |= 2;
    iouv[i] = best;
    meta[i] = (bestg << 2) | f;
  }
  __syncthreads();
  // --- build sort keys: (value desc, index asc), filler sorts last ---
  for (int i = tid; i < 2048; i += 1024) {
    unsigned long long k = 0ull;
    if (i < NN) {
      int m = meta[i];
      bool ok = which == 0 ? ((m & 1) != 0) : ((m & 2) != 0);
      float v = ok ? iouv[i] : -1.0f;            // matches jnp.where(cond, val, -1.0)
      k = (((unsigned long long)ord_f32(v)) << 32) | (unsigned long long)(2047 - i);
    }
    keys[i] = k;
  }
  __syncthreads();
  // --- bitonic sort, descending ---
  for (int kk = 2; kk <= 2048; kk <<= 1) {
    for (int j = kk >> 1; j > 0; j >>= 1) {
      for (int i = tid; i < 2048; i += 1024) {
        int ixj = i ^ j;
        if (ixj > i) {
          unsigned long long a = keys[i], c = keys[ixj];
          bool up = ((i & kk) == 0);
          if (up ? (a < c) : (a > c)) { keys[i] = c; keys[ixj] = a; }
        }
      }
      __syncthreads();
    }
  }
  // --- epilogue ---
  if (which == 0) {
    if (tid < PP) {
      int i = 2047 - (int)(keys[tid] & 0xFFFFFFFFull);
      int m = meta[i];
      int ok = m & 1;
      int g = m >> 2;
      long long e = (long long)(b * NN + i) * 4;
      float p0 = load_box_c(props, e + 0, bmode), p1 = load_box_c(props, e + 1, bmode);
      float p2 = load_box_c(props, e + 2, bmode), p3 = load_box_c(props, e + 3, bmode);
      float r0 = 0, r1 = 0, r2 = 0, r3 = 0, d0 = 0, d1 = 0, d2 = 0, d3 = 0, cid = 0.0f;
      if (ok) {
        r0 = p0; r1 = p1; r2 = p2; r3 = p3;
        cid = (float)gcls[g];
        float h = p2 - p0, w = p3 - p1;
        float cy = p0 + 0.5f * h, cx = p1 + 0.5f * w;
        float gh = gt2[g] - gt0[g], gw = gt3[g] - gt1[g];
        float gcy = gt0[g] + 0.5f * gh, gcx = gt1[g] + 0.5f * gw;
        d0 = ((gcy - cy) / h) / 0.1f;
        d1 = ((gcx - cx) / w) / 0.1f;
        d2 = logf(gh / h) / 0.2f;
        d3 = logf(gw / w) / 0.2f;
      }
      int row = b * TT + tid;
      int rb = row * 4;
      out[rb + 0] = r0; out[rb + 1] = r1; out[rb + 2] = r2; out[rb + 3] = r3;
      out[1600 + row] = cid;
      int db = 2000 + row * 4;
      out[db + 0] = d0; out[db + 1] = d1; out[db + 2] = d2; out[db + 3] = d3;
      // pos descriptor for mask kernel
      wbox[b * PP + tid] = make_float4(p0, p1, p2, p3);
      wokg[b * PP + tid] = (g << 1) | ok;
    }
  } else {
    if (tid < NEGN) {
      int j = 2047 - (int)(keys[tid] & 0xFFFFFFFFull);
      int ok = (meta[j] >> 1) & 1;
      float r0 = 0, r1 = 0, r2 = 0, r3 = 0;
      if (ok) {
        long long e = (long long)(b * NN + j) * 4;
        r0 = load_box_c(props, e + 0, bmode); r1 = load_box_c(props, e + 1, bmode);
        r2 = load_box_c(props, e + 2, bmode); r3 = load_box_c(props, e + 3, bmode);
      }
      int row = b * TT + PP + tid;
      int rb = row * 4;
      out[rb + 0] = r0; out[rb + 1] = r1; out[rb + 2] = r2; out[rb + 3] = r3;
      out[1600 + row] = 0.0f;
      int db = 2000 + row * 4;
      out[db + 0] = 0.0f; out[db + 1] = 0.0f; out[db + 2] = 0.0f; out[db + 3] = 0.0f;
    }
  }
}

// ---- 28x28 bilinear mask crops ----
__global__ void mask_kernel(const void* gmask, const float4* wbox, const int* wokg,
                            const int* wmode, float* out) {
#pragma clang fp contract(off)
  int blk = blockIdx.x;                 // b*T + t
  int b = blk / TT, t = blk - b * TT;
  float* mout = out + 3600 + (size_t)blk * (MHH * MWW);
  int ok = 0, g = 0;
  float by1 = 0, bx1 = 0, by2 = 0, bx2 = 0;
  if (t < PP) {
    int og = wokg[b * PP + t];
    ok = og & 1;
    g = og >> 1;
    float4 bx = wbox[b * PP + t];
    by1 = bx.x; bx1 = bx.y; by2 = bx.z; bx2 = bx.w;
  }
  if (!ok) {
    for (int p = threadIdx.x; p < MHH * MWW; p += blockDim.x)
      mout[p] = 0.0f;
    return;
  }
  int mmode = *wmode;
  for (int p = threadIdx.x; p < MHH * MWW; p += blockDim.x) {
    int yy = p / MWW, xx = p - yy * MWW;
    // ys = by1*(H-1) + ((i/(MH-1)) * (by2-by1)) * (H-1)   — exact op order of reference
    float ty = (float)yy / 27.0f;
    float ys = by1 * 799.0f + (ty * (by2 - by1)) * 799.0f;
    float tx = (float)xx / 27.0f;
    float xs = bx1 * 799.0f + (tx * (bx2 - bx1)) * 799.0f;
    float y0f = floorf(ys), x0f = floorf(xs);
    float wy = ys - y0f, wx = xs - x0f;
    int y0 = (int)y0f; if (y0 < 0) y0 = 0; if (y0 > HH - 1) y0 = HH - 1;
    int y1 = y0 + 1;   if (y1 > HH - 1) y1 = HH - 1;
    int x0 = (int)x0f; if (x0 < 0) x0 = 0; if (x0 > WW - 1) x0 = WW - 1;
    int x1 = x0 + 1;   if (x1 > WW - 1) x1 = WW - 1;
    size_t rowb = (size_t)b * HH;
    size_t i00 = ((rowb + y0) * WW + x0) * GG + g;
    size_t i01 = ((rowb + y0) * WW + x1) * GG + g;
    size_t i10 = ((rowb + y1) * WW + x0) * GG + g;
    size_t i11 = ((rowb + y1) * WW + x1) * GG + g;
    float v00 = load_mask(gmask, i00, mmode);
    float v01 = load_mask(gmask, i01, mmode);
    float v10 = load_mask(gmask, i10, mmode);
    float v11 = load_mask(gmask, i11, mmode);
    float top = v00 * (1.0f - wx) + v01 * wx;
    float bot = v10 * (1.0f - wx) + v11 * wx;
    float m = top * (1.0f - wy) + bot * wy;
    m = rintf(m);                       // jnp.round = round-half-to-even
    mout[p] = m;
  }
}

extern "C" void kernel_launch(void* const* d_in, const int* in_sizes, int n_in,
                              void* d_out, int out_size, void* d_ws, size_t ws_size,
                              hipStream_t stream) {
  const void* props = d_in[0];
  const int* cls = (const int*)d_in[1];
  const void* gtb = d_in[2];
  const void* gmask = d_in[3];
  char* ws = (char*)d_ws;
  float4* wbox = (float4*)(ws + WS_BOX);
  int* wokg    = (int*)(ws + WS_OKG);
  int* wmode   = (int*)(ws + WS_MODE);
  float* out = (float*)d_out;

  fused_kernel<<<BB * 2, 1024, 0, stream>>>(props, cls, gtb,
                                            (const unsigned int*)props,
                                            (const unsigned int*)gmask,
                                            out, wbox, wokg, wmode);
  mask_kernel<<<BB * TT, 256, 0, stream>>>(gmask, wbox, wokg, wmode, out);
}